// Round 11
// baseline (65.297 us; speedup 1.0000x reference)
//
#include <hip/hip_runtime.h>

typedef __attribute__((ext_vector_type(2))) float f2;

#define WAIT_LDS asm volatile("s_waitcnt lgkmcnt(0)" ::: "memory")

__device__ __forceinline__ f2 mk(float a, float b){ f2 r; r.x=a; r.y=b; return r; }

// ---------- DPP helpers (VALU cross-lane, no DS pipe) ----------
template<int CTRL>
__device__ __forceinline__ float dpp_add(float v){
  int t = __builtin_amdgcn_update_dpp(0, __builtin_bit_cast(int, v), CTRL, 0xF, 0xF, true);
  return v + __builtin_bit_cast(float, t);
}
__device__ __forceinline__ float wave_red_bcast(float v){
  v = dpp_add<0x111>(v);   // row_shr:1
  v = dpp_add<0x112>(v);   // row_shr:2
  v = dpp_add<0x114>(v);   // row_shr:4
  v = dpp_add<0x118>(v);   // row_shr:8
  v = dpp_add<0x142>(v);   // row_bcast:15
  v = dpp_add<0x143>(v);   // row_bcast:31
  return __builtin_bit_cast(float, __builtin_amdgcn_readlane(__builtin_bit_cast(int, v), 63));
}
template<int CTRL>
__device__ __forceinline__ float dpp_qp(float v){
  int t = __builtin_amdgcn_update_dpp(0, __builtin_bit_cast(int, v), CTRL, 0xF, 0xF, true);
  return __builtin_bit_cast(float, t);
}
#define XT(V,o) ((o)==1 ? dpp_qp<0xB1>(V) : (o)==2 ? dpp_qp<0x4E>(V) : __shfl_xor((V),(o)))

// ---------- packed complex, gate operand in SGPR pair ----------
__device__ __forceinline__ void cmadS(f2& c, f2 g, f2 b){
  asm("v_pk_fma_f32 %0, %1, %2, %0 op_sel:[0,0,0] op_sel_hi:[0,1,1]\n\t"
      "v_pk_fma_f32 %0, %1, %2, %0 op_sel:[1,1,0] op_sel_hi:[1,0,1] neg_lo:[1,0,0]"
      : "+v"(c) : "s"(g), "v"(b));
}
__device__ __forceinline__ f2 cmulS(f2 g, f2 b){
  f2 d;
  asm("v_pk_mul_f32 %0, %1, %2 op_sel:[0,0] op_sel_hi:[0,1]\n\t"
      "v_pk_fma_f32 %0, %1, %2, %0 op_sel:[1,1,0] op_sel_hi:[1,0,1] neg_lo:[1,0,0]"
      : "=&v"(d) : "s"(g), "v"(b));
  return d;
}
__device__ __forceinline__ void quadS(const f2* __restrict__ G, f2& a0, f2& a1, f2& a2, f2& a3){
  f2 c0,c1,c2,c3;
  c0=cmulS(G[0],a0);  c1=cmulS(G[1],a0);  c2=cmulS(G[2],a0);  c3=cmulS(G[3],a0);
  cmadS(c0,G[4],a1);  cmadS(c1,G[5],a1);  cmadS(c2,G[6],a1);  cmadS(c3,G[7],a1);
  cmadS(c0,G[8],a2);  cmadS(c1,G[9],a2);  cmadS(c2,G[10],a2); cmadS(c3,G[11],a2);
  cmadS(c0,G[12],a3); cmadS(c1,G[13],a3); cmadS(c2,G[14],a3); cmadS(c3,G[15],a3);
  a0=c0; a1=c1; a2=c2; a3=c3;
}

// ---------- scalar complex (setup only) ----------
__device__ __forceinline__ float2 cmul(float2 a, float2 b){
  return make_float2(a.x*b.x - a.y*b.y, a.x*b.y + a.y*b.x);
}
__device__ __forceinline__ float2 cmad(float2 acc, float2 a, float2 b){
  acc.x += a.x*b.x - a.y*b.y; acc.y += a.x*b.y + a.y*b.x; return acc;
}

// ---------- setup: data-driven interpreter, tiny code (I$-friendly) ----------
__global__ __launch_bounds__(64) void qm_setup(
    const float* __restrict__ params, const float* __restrict__ w_fc,
    const float* __restrict__ b_in, const float* __restrict__ b_fc,
    float* __restrict__ wsf){
  __shared__ float2 m2[50][4];
  __shared__ float2 h4[10][16];
  const int t = threadIdx.x;

  if (t < 50){
    int typ[5], pix[5], ng;
    if (t < 40){
      int i = t>>3, k = t&7;
      int P1 = 10 + i*12, P2 = 70 + i*12;
      switch(k){
        case 0: ng=5; typ[0]=3;pix[0]=0;     typ[1]=1;pix[1]=2*i;   typ[2]=0;pix[2]=P1+0;
                      typ[3]=1;pix[3]=P1+2;  typ[4]=2;pix[4]=P1+4;  break;
        case 1: ng=5; typ[0]=3;pix[0]=0;     typ[1]=1;pix[1]=2*i+1; typ[2]=1;pix[2]=P1+1;
                      typ[3]=2;pix[3]=P1+3;  typ[4]=0;pix[4]=P1+5;  break;
        case 2: ng=3; typ[0]=2;pix[0]=P1+6;  typ[1]=1;pix[1]=P1+8;  typ[2]=0;pix[2]=P1+10; break;
        case 3: ng=3; typ[0]=0;pix[0]=P1+7;  typ[1]=2;pix[1]=P1+9;  typ[2]=1;pix[2]=P1+11; break;
        case 4: ng=3; typ[0]=0;pix[0]=P2+0;  typ[1]=1;pix[1]=P2+2;  typ[2]=2;pix[2]=P2+4;  break;
        case 5: ng=3; typ[0]=1;pix[0]=P2+1;  typ[1]=2;pix[1]=P2+3;  typ[2]=0;pix[2]=P2+5;  break;
        case 6: ng=3; typ[0]=2;pix[0]=P2+6;  typ[1]=1;pix[1]=P2+8;  typ[2]=0;pix[2]=P2+10; break;
        default:ng=3; typ[0]=0;pix[0]=P2+7;  typ[1]=2;pix[1]=P2+9;  typ[2]=1;pix[2]=P2+11; break;
      }
    } else {
      int S = 130 + (t-40)*3;
      ng=3; typ[0]=2;pix[0]=S+0; typ[1]=1;pix[1]=S+1; typ[2]=2;pix[2]=S+2;
    }
    float2 M[4] = {{1.f,0.f},{0.f,0.f},{0.f,0.f},{1.f,0.f}};
    #pragma clang loop unroll(disable)
    for (int g=0; g<ng; ++g){
      float2 R[4];
      if (typ[g]==3){
        const float r_=0.70710678118654752f;
        R[0]={r_,0.f}; R[1]={r_,0.f}; R[2]={r_,0.f}; R[3]={-r_,0.f};
      } else {
        float th = params[pix[g]]*0.5f;
        float c = cosf(th), s = sinf(th);
        if (typ[g]==0){ R[0]={c,0.f}; R[1]={0.f,-s}; R[2]={0.f,-s}; R[3]={c,0.f}; }
        else if (typ[g]==1){ R[0]={c,0.f}; R[1]={-s,0.f}; R[2]={s,0.f}; R[3]={c,0.f}; }
        else { R[0]={c,-s}; R[1]={0.f,0.f}; R[2]={0.f,0.f}; R[3]={c,s}; }
      }
      float2 T0=cmad(cmul(R[0],M[0]), R[1], M[2]);
      float2 T1=cmad(cmul(R[0],M[1]), R[1], M[3]);
      float2 T2=cmad(cmul(R[2],M[0]), R[3], M[2]);
      float2 T3=cmad(cmul(R[2],M[1]), R[3], M[3]);
      M[0]=T0; M[1]=T1; M[2]=T2; M[3]=T3;
    }
    m2[t][0]=M[0]; m2[t][1]=M[1]; m2[t][2]=M[2]; m2[t][3]=M[3];
  }
  __syncthreads();
  if (t < 10){                                   // vqc half: CNOT*(A2xB2)*CZ*(A1xB1)
    int i = t>>1, L = t&1;
    const float2* A1 = m2[i*8 + L*4 + 0];
    const float2* B1 = m2[i*8 + L*4 + 1];
    const float2* A2 = m2[i*8 + L*4 + 2];
    const float2* B2 = m2[i*8 + L*4 + 3];
    float2 K1[16], K2[16];
    #pragma clang loop unroll(disable)
    for (int r=0;r<4;r++)
      #pragma clang loop unroll(disable)
      for (int c=0;c<4;c++){
        K1[r*4+c] = cmul(A1[(r>>1)*2+(c>>1)], B1[(r&1)*2+(c&1)]);
        K2[r*4+c] = cmul(A2[(r>>1)*2+(c>>1)], B2[(r&1)*2+(c&1)]);
      }
    #pragma clang loop unroll(disable)
    for (int c=0;c<4;c++){ K1[12+c].x=-K1[12+c].x; K1[12+c].y=-K1[12+c].y; }  // CZ
    #pragma clang loop unroll(disable)
    for (int r=0;r<4;r++){
      int rr = (r==1)?3:(r==3)?1:r;                                          // CNOT row swap
      #pragma clang loop unroll(disable)
      for (int c=0;c<4;c++){
        float2 v = cmul(K2[r*4+0], K1[0+c]);
        v = cmad(v, K2[r*4+1], K1[4+c]);
        v = cmad(v, K2[r*4+2], K1[8+c]);
        v = cmad(v, K2[r*4+3], K1[12+c]);
        h4[t][rr*4+c] = v;
      }
    }
  }
  __syncthreads();
  if (t < 5){                                    // G = H_L2 @ H_L1, col-major out
    const float2* Ga = h4[t*2+1];
    const float2* Gb = h4[t*2+0];
    float2* dst = (float2*)wsf + t*16;
    #pragma clang loop unroll(disable)
    for (int r=0;r<4;r++)
      #pragma clang loop unroll(disable)
      for (int c=0;c<4;c++){
        float2 v = cmul(Ga[r*4+0], Gb[0+c]);
        v = cmad(v, Ga[r*4+1], Gb[4+c]);
        v = cmad(v, Ga[r*4+2], Gb[8+c]);
        v = cmad(v, Ga[r*4+3], Gb[12+c]);
        dst[c*4+r] = v;
      }
  } else if (t < 10){                            // rot pair kron, col-major out
    int i = t-5;
    const float2* Ra = m2[40 + 2*i];
    const float2* Rb = m2[40 + 2*i + 1];
    float2* dst = (float2*)wsf + 80 + i*16;
    #pragma clang loop unroll(disable)
    for (int r=0;r<4;r++)
      #pragma clang loop unroll(disable)
      for (int c=0;c<4;c++)
        dst[c*4+r] = cmul(Ra[(r>>1)*2+(c>>1)], Rb[(r&1)*2+(c&1)]);
  } else if (t < 20){                            // cbias = b_fc + w_fc @ b_in
    int c = t-10;
    float s = b_fc[c];
    #pragma clang loop unroll(disable)
    for (int q=0;q<10;q++) s += w_fc[c*10+q]*b_in[q];
    wsf[320+c] = s;
  }
}

// ---------- layout forms (GF2-linear, compile-time per k) ----------
template<int F> __device__ __forceinline__ int ckf(int k){
  if constexpr (F==1) return (((k<<6) ^ ((k&3)<<2)) << 3);
  else if constexpr (F==2) return (((k<<2) ^ (k>>2)) << 3);
  else if constexpr (F==3){ constexpr int IOFF[4]={0,0x6,0xC,0xA}; return ((IOFF[k>>2] ^ (k&3)) << 3); }
  else if constexpr (F==4){ constexpr int PJ[4]={0,0x201,0x203,0x002}; return (((k&0xC) ^ PJ[k&3]) << 3); }
  else return ((((k>>2)<<4) ^ (k>>2) ^ (k&3)) << 3);
}
template<int F> __device__ __forceinline__ void stA(char* PB, int L, const f2* A){
  #pragma unroll
  for (int k=0;k<16;k++) *(f2*)(PB + (L ^ ckf<F>(k))) = A[k];
}
template<int F> __device__ __forceinline__ void ldA(char* PB, int L, f2* A){
  #pragma unroll
  for (int k=0;k<16;k++) A[k] = *(const f2*)(PB + (L ^ ckf<F>(k)));
}
__device__ __forceinline__ void gij(const f2* Gi, const f2* Gj, f2* A){
  #pragma unroll
  for (int j=0;j<4;j++) quadS(Gi, A[j], A[4+j], A[8+j], A[12+j]);
  #pragma unroll
  for (int i=0;i<4;i++) quadS(Gj, A[4*i], A[4*i+1], A[4*i+2], A[4*i+3]);
}
__device__ __forceinline__ void g3(const f2* G10, const f2* Gr32, f2* A){
  quadS(G10, A[0], A[1], A[2], A[3]);
  quadS(G10, A[6], A[7], A[4], A[5]);
  quadS(G10, A[8], A[9], A[10], A[11]);
  quadS(G10, A[14], A[15], A[12], A[13]);
  #pragma unroll
  for (int j=0;j<4;j++) quadS(Gr32, A[j], A[4+j], A[8+j], A[12+j]);
}

// ---------- GEMV partials + norm + strided row sample ----------
__device__ __forceinline__ void gemv(const float* __restrict__ xr, const float* __restrict__ w_in,
                                     int l, float* xp, float* xs, float& n2raw){
  float4 xv0 = *(const float4*)(xr + (l<<4));
  float4 xv1 = *(const float4*)(xr + (l<<4) + 4);
  float4 xv2 = *(const float4*)(xr + (l<<4) + 8);
  float4 xv3 = *(const float4*)(xr + (l<<4) + 12);
  f2 xc[8];
  xc[0]=mk(xv0.x,xv0.y); xc[1]=mk(xv0.z,xv0.w); xc[2]=mk(xv1.x,xv1.y); xc[3]=mk(xv1.z,xv1.w);
  xc[4]=mk(xv2.x,xv2.y); xc[5]=mk(xv2.z,xv2.w); xc[6]=mk(xv3.x,xv3.y); xc[7]=mk(xv3.z,xv3.w);
  #pragma unroll
  for (int q=0;q<10;q++){
    const float4* wr = (const float4*)(w_in + (q<<10) + (l<<4));
    float4 w0=wr[0], w1=wr[1], w2=wr[2], w3=wr[3];
    f2 a;
    a  = xc[0]*mk(w0.x,w0.y);
    a += xc[1]*mk(w0.z,w0.w);
    a += xc[2]*mk(w1.x,w1.y);
    a += xc[3]*mk(w1.z,w1.w);
    a += xc[4]*mk(w2.x,w2.y);
    a += xc[5]*mk(w2.z,w2.w);
    a += xc[6]*mk(w3.x,w3.y);
    a += xc[7]*mk(w3.z,w3.w);
    xp[q] = a.x + a.y;
  }
  f2 nn = xc[0]*xc[0]; nn += xc[1]*xc[1]; nn += xc[2]*xc[2]; nn += xc[3]*xc[3];
  nn += xc[4]*xc[4]; nn += xc[5]*xc[5]; nn += xc[6]*xc[6]; nn += xc[7]*xc[7];
  n2raw = nn.x + nn.y;
  #pragma unroll
  for (int k=0;k<16;k++) xs[k] = xr[(k<<6)|l];
}

// Walsh butterfly helpers (signed / plain / split combine); o=1,2 on VALU DPP
#define SGN_IP(V, o) { float t_=XT(V,o); float d_=V-t_; V = (l&(o))?-d_:d_; }
#define PLAIN_IP(V, o) { V += XT(V,o); }
#define SPLIT(Vp, Vs, V, o) { float t_=XT(V,o); Vp = V+t_; float d_=V-t_; Vs=(l&(o))?-d_:d_; }

// all 10 signed marginals (ring2 folded as Walsh masks); W[0..9] per current layout
__device__ __forceinline__ void walsh(const f2* A, int l, float* W){
  float p[16];
  #pragma unroll
  for (int k=0;k<16;k++){ f2 sq = A[k]*A[k]; p[k] = sq.x + sq.y; }
  float sg[4], eg[4], fg[4];
  #pragma unroll
  for (int g=0; g<4; ++g){
    float a_=p[4*g]+p[4*g+1], b_=p[4*g+2]+p[4*g+3];
    float c_=p[4*g]-p[4*g+1], d_=p[4*g+2]-p[4*g+3];
    sg[g]=a_+b_; eg[g]=a_-b_; fg[g]=c_-d_;
  }
  float s01=sg[0]+sg[1], s23=sg[2]+sg[3];
  float d01=sg[0]-sg[1], d23=sg[2]-sg[3];
  float S  = s01+s23;
  float W8 = s01-s23;
  float WC = d01-d23;
  float WE = (eg[0]-eg[1])-(eg[2]-eg[3]);
  float WF = (fg[0]-fg[1])-(fg[2]-fg[3]);
  float WCp, WCs, WCpp, WCps, WCss, Sp, Ss, Spp, Sps, q0;
  PLAIN_IP(S,1); PLAIN_IP(W8,1); SPLIT(WCp, WCs, WC, 1); SGN_IP(WE,1); SGN_IP(WF,1);
  PLAIN_IP(S,2); PLAIN_IP(W8,2); SPLIT(WCpp, WCps, WCp, 2); SGN_IP(WCs,2); SGN_IP(WE,2); SGN_IP(WF,2);
  WCss = WCs;
  SPLIT(Sp, Ss, S, 4); SGN_IP(W8,4); SGN_IP(WCpp,4); SGN_IP(WCps,4); SGN_IP(WCss,4); SGN_IP(WE,4); SGN_IP(WF,4);
  SPLIT(Spp, Sps, Sp, 8); SGN_IP(Ss,8); SGN_IP(W8,8); SGN_IP(WCpp,8); SGN_IP(WCps,8); SGN_IP(WCss,8); SGN_IP(WE,8); SGN_IP(WF,8);
  SGN_IP(Spp,16); SGN_IP(Sps,16); SGN_IP(Ss,16); SGN_IP(W8,16); SGN_IP(WCpp,16);
  SGN_IP(WCps,16); SGN_IP(WCss,16); SGN_IP(WE,16); SGN_IP(WF,16);
  SGN_IP(Spp,32); SGN_IP(Sps,32); SGN_IP(Ss,32); SGN_IP(W8,32); SGN_IP(WCpp,32);
  SGN_IP(WCps,32); SGN_IP(WCss,32); SGN_IP(WE,32);
  { float t_=__shfl_xor(WF,32); q0 = WF+t_; float d_=WF-t_; WF=(l&32)?-d_:d_; }
  W[0]=q0; W[1]=Spp; W[2]=Sps; W[3]=Ss; W[4]=W8;
  W[5]=WCpp; W[6]=WCps; W[7]=WCss; W[8]=WE; W[9]=WF;
}

// ---------- main: one WAVE = TWO samples (ILP); 2-wave blocks; 5 rounds ----------
__global__ __launch_bounds__(128,2) void qm_sim(
    const float* __restrict__ x, const float* __restrict__ w_in,
    const float* __restrict__ w_fc, const float* __restrict__ wsf,
    float* __restrict__ out)
{
  __shared__ __align__(16) f2 psi[4096];               // 2 waves x 2 samples x 1024
  const int t = threadIdx.x;
  const int l = t & 63, wid = t >> 6;
  const int s0 = (blockIdx.x<<2) + (wid<<1), s1 = s0 + 1;
  char* PB0 = (char*)(psi + (wid<<11));
  char* PB1 = PB0 + 8192;
  const float* xr0 = x + ((size_t)s0<<10);
  const float* xr1 = x + ((size_t)s1<<10);
  const f2* G = (const f2*)wsf;                        // gates: uniform -> scalar loads

  float xp0[10], xp1[10], xs0[16], xs1[16], n2a, n2b;
  gemv(xr0, w_in, l, xp0, xs0, n2a);
  gemv(xr1, w_in, l, xp1, xs1, n2b);
  float rn0 = rsqrtf(wave_red_bcast(n2a));
  float rn1 = rsqrtf(wave_red_bcast(n2b));

  const int Lb  = (l ^ (l>>4)) << 3;
  const int L2  = ((((l>>2)<<6)) ^ (l&3) ^ (l&0xC)) << 3;
  const int L3  = (((l<<4) ^ (l<<3)) ^ ((l ^ (l>>1)) & 15)) << 3;
  const int L3w = ((l<<4) ^ (l&15)) << 3;
  const int L5  = ((((l>>2)<<6)) ^ ((l&3)<<2) ^ (l&0xC)) << 3;

  // ===== R1 =====
  f2 A0[16], A1[16];
  #pragma unroll
  for (int k=0;k<16;k++){ A0[k] = mk(xs0[k]*rn0, 0.f); A1[k] = mk(xs1[k]*rn1, 0.f); }
  gij(G+ 0, G+16, A0);  gij(G+ 0, G+16, A1);           // G98, G76
  stA<1>(PB0, Lb, A0);  stA<1>(PB1, Lb, A1);
  WAIT_LDS;
  // ===== R2 =====
  ldA<2>(PB0, L2, A0);  ldA<2>(PB1, L2, A1);
  gij(G+32, G+48, A0);  gij(G+32, G+48, A1);           // G54, G32
  stA<2>(PB0, L2, A0);  stA<2>(PB1, L2, A1);
  WAIT_LDS;
  // ===== R3: G10 + ring perm + rot32 =====
  ldA<3>(PB0, L3, A0);  ldA<3>(PB1, L3, A1);
  g3(G+64, G+128, A0);  g3(G+64, G+128, A1);
  stA<4>(PB0, L3w, A0); stA<4>(PB1, L3w, A1);
  WAIT_LDS;
  // ===== R4 =====
  ldA<1>(PB0, Lb, A0);  ldA<1>(PB1, Lb, A1);
  gij(G+80, G+96, A0);  gij(G+80, G+96, A1);           // rot98, rot76
  stA<1>(PB0, Lb, A0);  stA<1>(PB1, Lb, A1);
  WAIT_LDS;
  // ===== R5 =====
  ldA<5>(PB0, L5, A0);  ldA<5>(PB1, L5, A1);
  gij(G+112, G+144, A0); gij(G+112, G+144, A1);        // rot54, rot10

  // ===== epilogue =====
  float W0[10], W1[10];
  walsh(A0, l, W0);
  walsh(A1, l, W1);
  float xq0[10], xq1[10];
  #pragma unroll
  for (int q=0;q<10;q++){ xq0[q] = wave_red_bcast(xp0[q]); xq1[q] = wave_red_bcast(xp1[q]); }

  if (l < 10){
    float cb = wsf[320+l];                             // b_fc + w_fc@b_in
    float wf[10];
    #pragma unroll
    for (int q=0;q<10;q++) wf[q] = w_fc[l*10+q];
    float o0 = cb, o1 = cb;
    #pragma unroll
    for (int q=0;q<10;q++){
      o0 += wf[q] * (W0[q] + xq0[q]);
      o1 += wf[q] * (W1[q] + xq1[q]);
    }
    out[(size_t)s0*10 + l] = o0;
    out[(size_t)s1*10 + l] = o1;
  }
}

extern "C" void kernel_launch(void* const* d_in, const int* in_sizes, int n_in,
                              void* d_out, int out_size, void* d_ws, size_t ws_size,
                              hipStream_t stream) {
  const float* x      = (const float*)d_in[0];
  const float* params = (const float*)d_in[1];
  const float* w_in   = (const float*)d_in[2];
  const float* b_in   = (const float*)d_in[3];
  const float* w_fc   = (const float*)d_in[4];
  const float* b_fc   = (const float*)d_in[5];
  float* out = (float*)d_out;

  float* wsf = (float*)d_ws;                        // 320 f gate mats + 10 f cbias

  int batch = in_sizes[0] >> 10;                    // 8192

  qm_setup<<<dim3(1), dim3(64), 0, stream>>>(params, w_fc, b_in, b_fc, wsf);
  qm_sim<<<dim3(batch>>2), dim3(128), 0, stream>>>(x, w_in, w_fc, wsf, out);
}

// Round 12
// 58.213 us; speedup vs baseline: 1.1217x; 1.1217x over previous
//
#include <hip/hip_runtime.h>

typedef __attribute__((ext_vector_type(2))) float f2;

#define WAIT_LDS asm volatile("s_waitcnt lgkmcnt(0)" ::: "memory")

__device__ __forceinline__ f2 mk(float a, float b){ f2 r; r.x=a; r.y=b; return r; }

// ---------- DPP helpers (VALU cross-lane, no DS pipe) ----------
template<int CTRL>
__device__ __forceinline__ float dpp_add(float v){
  int t = __builtin_amdgcn_update_dpp(0, __builtin_bit_cast(int, v), CTRL, 0xF, 0xF, true);
  return v + __builtin_bit_cast(float, t);
}
__device__ __forceinline__ float wave_red_bcast(float v){
  v = dpp_add<0x111>(v);   // row_shr:1
  v = dpp_add<0x112>(v);   // row_shr:2
  v = dpp_add<0x114>(v);   // row_shr:4
  v = dpp_add<0x118>(v);   // row_shr:8
  v = dpp_add<0x142>(v);   // row_bcast:15
  v = dpp_add<0x143>(v);   // row_bcast:31
  return __builtin_bit_cast(float, __builtin_amdgcn_readlane(__builtin_bit_cast(int, v), 63));
}
template<int CTRL>
__device__ __forceinline__ float dpp_qp(float v){
  int t = __builtin_amdgcn_update_dpp(0, __builtin_bit_cast(int, v), CTRL, 0xF, 0xF, true);
  return __builtin_bit_cast(float, t);
}
#define XT(V,o) ((o)==1 ? dpp_qp<0xB1>(V) : (o)==2 ? dpp_qp<0x4E>(V) : __shfl_xor((V),(o)))

// ---------- packed complex, gate operand in SGPR pair ----------
__device__ __forceinline__ void cmadS(f2& c, f2 g, f2 b){
  asm("v_pk_fma_f32 %0, %1, %2, %0 op_sel:[0,0,0] op_sel_hi:[0,1,1]\n\t"
      "v_pk_fma_f32 %0, %1, %2, %0 op_sel:[1,1,0] op_sel_hi:[1,0,1] neg_lo:[1,0,0]"
      : "+v"(c) : "s"(g), "v"(b));
}
__device__ __forceinline__ f2 cmulS(f2 g, f2 b){
  f2 d;
  asm("v_pk_mul_f32 %0, %1, %2 op_sel:[0,0] op_sel_hi:[0,1]\n\t"
      "v_pk_fma_f32 %0, %1, %2, %0 op_sel:[1,1,0] op_sel_hi:[1,0,1] neg_lo:[1,0,0]"
      : "=&v"(d) : "s"(g), "v"(b));
  return d;
}
__device__ __forceinline__ void quadS(const f2* __restrict__ G, f2& a0, f2& a1, f2& a2, f2& a3){
  f2 c0,c1,c2,c3;
  c0=cmulS(G[0],a0);  c1=cmulS(G[1],a0);  c2=cmulS(G[2],a0);  c3=cmulS(G[3],a0);
  cmadS(c0,G[4],a1);  cmadS(c1,G[5],a1);  cmadS(c2,G[6],a1);  cmadS(c3,G[7],a1);
  cmadS(c0,G[8],a2);  cmadS(c1,G[9],a2);  cmadS(c2,G[10],a2); cmadS(c3,G[11],a2);
  cmadS(c0,G[12],a3); cmadS(c1,G[13],a3); cmadS(c2,G[14],a3); cmadS(c3,G[15],a3);
  a0=c0; a1=c1; a2=c2; a3=c3;
}

// ---------- scalar complex (setup only) ----------
__device__ __forceinline__ float2 cmul(float2 a, float2 b){
  return make_float2(a.x*b.x - a.y*b.y, a.x*b.y + a.y*b.x);
}
__device__ __forceinline__ float2 cmad(float2 acc, float2 a, float2 b){
  acc.x += a.x*b.x - a.y*b.y; acc.y += a.x*b.y + a.y*b.x; return acc;
}

// ---------- setup: data-driven interpreter (unchanged, ~5us) ----------
__global__ __launch_bounds__(64) void qm_setup(
    const float* __restrict__ params, const float* __restrict__ w_fc,
    const float* __restrict__ b_in, const float* __restrict__ b_fc,
    float* __restrict__ wsf){
  __shared__ float2 m2[50][4];
  __shared__ float2 h4[10][16];
  const int t = threadIdx.x;

  if (t < 50){
    int typ[5], pix[5], ng;
    if (t < 40){
      int i = t>>3, k = t&7;
      int P1 = 10 + i*12, P2 = 70 + i*12;
      switch(k){
        case 0: ng=5; typ[0]=3;pix[0]=0;     typ[1]=1;pix[1]=2*i;   typ[2]=0;pix[2]=P1+0;
                      typ[3]=1;pix[3]=P1+2;  typ[4]=2;pix[4]=P1+4;  break;
        case 1: ng=5; typ[0]=3;pix[0]=0;     typ[1]=1;pix[1]=2*i+1; typ[2]=1;pix[2]=P1+1;
                      typ[3]=2;pix[3]=P1+3;  typ[4]=0;pix[4]=P1+5;  break;
        case 2: ng=3; typ[0]=2;pix[0]=P1+6;  typ[1]=1;pix[1]=P1+8;  typ[2]=0;pix[2]=P1+10; break;
        case 3: ng=3; typ[0]=0;pix[0]=P1+7;  typ[1]=2;pix[1]=P1+9;  typ[2]=1;pix[2]=P1+11; break;
        case 4: ng=3; typ[0]=0;pix[0]=P2+0;  typ[1]=1;pix[1]=P2+2;  typ[2]=2;pix[2]=P2+4;  break;
        case 5: ng=3; typ[0]=1;pix[0]=P2+1;  typ[1]=2;pix[1]=P2+3;  typ[2]=0;pix[2]=P2+5;  break;
        case 6: ng=3; typ[0]=2;pix[0]=P2+6;  typ[1]=1;pix[1]=P2+8;  typ[2]=0;pix[2]=P2+10; break;
        default:ng=3; typ[0]=0;pix[0]=P2+7;  typ[1]=2;pix[1]=P2+9;  typ[2]=1;pix[2]=P2+11; break;
      }
    } else {
      int S = 130 + (t-40)*3;
      ng=3; typ[0]=2;pix[0]=S+0; typ[1]=1;pix[1]=S+1; typ[2]=2;pix[2]=S+2;
    }
    float2 M[4] = {{1.f,0.f},{0.f,0.f},{0.f,0.f},{1.f,0.f}};
    #pragma clang loop unroll(disable)
    for (int g=0; g<ng; ++g){
      float2 R[4];
      if (typ[g]==3){
        const float r_=0.70710678118654752f;
        R[0]={r_,0.f}; R[1]={r_,0.f}; R[2]={r_,0.f}; R[3]={-r_,0.f};
      } else {
        float th = params[pix[g]]*0.5f;
        float c = cosf(th), s = sinf(th);
        if (typ[g]==0){ R[0]={c,0.f}; R[1]={0.f,-s}; R[2]={0.f,-s}; R[3]={c,0.f}; }
        else if (typ[g]==1){ R[0]={c,0.f}; R[1]={-s,0.f}; R[2]={s,0.f}; R[3]={c,0.f}; }
        else { R[0]={c,-s}; R[1]={0.f,0.f}; R[2]={0.f,0.f}; R[3]={c,s}; }
      }
      float2 T0=cmad(cmul(R[0],M[0]), R[1], M[2]);
      float2 T1=cmad(cmul(R[0],M[1]), R[1], M[3]);
      float2 T2=cmad(cmul(R[2],M[0]), R[3], M[2]);
      float2 T3=cmad(cmul(R[2],M[1]), R[3], M[3]);
      M[0]=T0; M[1]=T1; M[2]=T2; M[3]=T3;
    }
    m2[t][0]=M[0]; m2[t][1]=M[1]; m2[t][2]=M[2]; m2[t][3]=M[3];
  }
  __syncthreads();
  if (t < 10){                                   // vqc half: CNOT*(A2xB2)*CZ*(A1xB1)
    int i = t>>1, L = t&1;
    const float2* A1 = m2[i*8 + L*4 + 0];
    const float2* B1 = m2[i*8 + L*4 + 1];
    const float2* A2 = m2[i*8 + L*4 + 2];
    const float2* B2 = m2[i*8 + L*4 + 3];
    float2 K1[16], K2[16];
    #pragma clang loop unroll(disable)
    for (int r=0;r<4;r++)
      #pragma clang loop unroll(disable)
      for (int c=0;c<4;c++){
        K1[r*4+c] = cmul(A1[(r>>1)*2+(c>>1)], B1[(r&1)*2+(c&1)]);
        K2[r*4+c] = cmul(A2[(r>>1)*2+(c>>1)], B2[(r&1)*2+(c&1)]);
      }
    #pragma clang loop unroll(disable)
    for (int c=0;c<4;c++){ K1[12+c].x=-K1[12+c].x; K1[12+c].y=-K1[12+c].y; }  // CZ
    #pragma clang loop unroll(disable)
    for (int r=0;r<4;r++){
      int rr = (r==1)?3:(r==3)?1:r;                                          // CNOT row swap
      #pragma clang loop unroll(disable)
      for (int c=0;c<4;c++){
        float2 v = cmul(K2[r*4+0], K1[0+c]);
        v = cmad(v, K2[r*4+1], K1[4+c]);
        v = cmad(v, K2[r*4+2], K1[8+c]);
        v = cmad(v, K2[r*4+3], K1[12+c]);
        h4[t][rr*4+c] = v;
      }
    }
  }
  __syncthreads();
  if (t < 5){                                    // G = H_L2 @ H_L1, col-major out
    const float2* Ga = h4[t*2+1];
    const float2* Gb = h4[t*2+0];
    float2* dst = (float2*)wsf + t*16;
    #pragma clang loop unroll(disable)
    for (int r=0;r<4;r++)
      #pragma clang loop unroll(disable)
      for (int c=0;c<4;c++){
        float2 v = cmul(Ga[r*4+0], Gb[0+c]);
        v = cmad(v, Ga[r*4+1], Gb[4+c]);
        v = cmad(v, Ga[r*4+2], Gb[8+c]);
        v = cmad(v, Ga[r*4+3], Gb[12+c]);
        dst[c*4+r] = v;
      }
  } else if (t < 10){                            // rot pair kron, col-major out
    int i = t-5;
    const float2* Ra = m2[40 + 2*i];
    const float2* Rb = m2[40 + 2*i + 1];
    float2* dst = (float2*)wsf + 80 + i*16;
    #pragma clang loop unroll(disable)
    for (int r=0;r<4;r++)
      #pragma clang loop unroll(disable)
      for (int c=0;c<4;c++)
        dst[c*4+r] = cmul(Ra[(r>>1)*2+(c>>1)], Rb[(r&1)*2+(c&1)]);
  } else if (t < 20){                            // cbias = b_fc + w_fc @ b_in
    int c = t-10;
    float s = b_fc[c];
    #pragma clang loop unroll(disable)
    for (int q=0;q<10;q++) s += w_fc[c*10+q]*b_in[q];
    wsf[320+c] = s;
  }
}

// ---------- transition address constants (validated forms; bit12 pre-masked) ----------
constexpr int CK1(int k){ return ((((k<<6) ^ ((k&3)<<2)) << 3) & 0xFFF); }   // bit12 was k3
constexpr int CK2(int k){ return (((k<<2) ^ (k>>2)) << 3); }
constexpr int CK3(int k){ constexpr int IOFF[4]={0,0x6,0xC,0xA}; return ((IOFF[k>>2] ^ (k&3)) << 3); }
constexpr int CK4(int k){ constexpr int PJ[4]={0,0x201,0x203,0x002};
                          return ((((k&0xC) ^ PJ[k&3]) << 3) & 0xFFF); }     // bit12 was pj9
constexpr int CK5(int k){ return ((((k>>2)<<4) ^ (k>>2) ^ (k&3)) << 3); }

__device__ __forceinline__ void gij(const f2* Gi, const f2* Gj, f2* A){
  #pragma unroll
  for (int j=0;j<4;j++) quadS(Gi, A[j], A[4+j], A[8+j], A[12+j]);
  #pragma unroll
  for (int i=0;i<4;i++) quadS(Gj, A[4*i], A[4*i+1], A[4*i+2], A[4*i+3]);
}
__device__ __forceinline__ void g3(const f2* G10, const f2* Gr32, f2* A){
  quadS(G10, A[0], A[1], A[2], A[3]);
  quadS(G10, A[6], A[7], A[4], A[5]);
  quadS(G10, A[8], A[9], A[10], A[11]);
  quadS(G10, A[14], A[15], A[12], A[13]);
  #pragma unroll
  for (int j=0;j<4;j++) quadS(Gr32, A[j], A[4+j], A[8+j], A[12+j]);
}

// Walsh butterfly helpers
#define SGN_IP(V, o) { float t_=XT(V,o); float d_=V-t_; V = (l&(o))?-d_:d_; }
#define PLAIN_IP(V, o) { V += XT(V,o); }
#define SPLIT(Vp, Vs, V, o) { float t_=XT(V,o); Vp = V+t_; float d_=V-t_; Vs=(l&(o))?-d_:d_; }

__device__ __forceinline__ void walsh(const f2* A, int l, float* W){
  float p[16];
  #pragma unroll
  for (int k=0;k<16;k++){ f2 sq = A[k]*A[k]; p[k] = sq.x + sq.y; }
  float sg[4], eg[4], fg[4];
  #pragma unroll
  for (int g=0; g<4; ++g){
    float a_=p[4*g]+p[4*g+1], b_=p[4*g+2]+p[4*g+3];
    float c_=p[4*g]-p[4*g+1], d_=p[4*g+2]-p[4*g+3];
    sg[g]=a_+b_; eg[g]=a_-b_; fg[g]=c_-d_;
  }
  float s01=sg[0]+sg[1], s23=sg[2]+sg[3];
  float d01=sg[0]-sg[1], d23=sg[2]-sg[3];
  float S  = s01+s23;
  float W8 = s01-s23;
  float WC = d01-d23;
  float WE = (eg[0]-eg[1])-(eg[2]-eg[3]);
  float WF = (fg[0]-fg[1])-(fg[2]-fg[3]);
  float WCp, WCs, WCpp, WCps, WCss, Sp, Ss, Spp, Sps, q0;
  PLAIN_IP(S,1); PLAIN_IP(W8,1); SPLIT(WCp, WCs, WC, 1); SGN_IP(WE,1); SGN_IP(WF,1);
  PLAIN_IP(S,2); PLAIN_IP(W8,2); SPLIT(WCpp, WCps, WCp, 2); SGN_IP(WCs,2); SGN_IP(WE,2); SGN_IP(WF,2);
  WCss = WCs;
  SPLIT(Sp, Ss, S, 4); SGN_IP(W8,4); SGN_IP(WCpp,4); SGN_IP(WCps,4); SGN_IP(WCss,4); SGN_IP(WE,4); SGN_IP(WF,4);
  SPLIT(Spp, Sps, Sp, 8); SGN_IP(Ss,8); SGN_IP(W8,8); SGN_IP(WCpp,8); SGN_IP(WCps,8); SGN_IP(WCss,8); SGN_IP(WE,8); SGN_IP(WF,8);
  SGN_IP(Spp,16); SGN_IP(Sps,16); SGN_IP(Ss,16); SGN_IP(W8,16); SGN_IP(WCpp,16);
  SGN_IP(WCps,16); SGN_IP(WCss,16); SGN_IP(WE,16); SGN_IP(WF,16);
  SGN_IP(Spp,32); SGN_IP(Sps,32); SGN_IP(Ss,32); SGN_IP(W8,32); SGN_IP(WCpp,32);
  SGN_IP(WCps,32); SGN_IP(WCss,32); SGN_IP(WE,32);
  { float t_=__shfl_xor(WF,32); q0 = WF+t_; float d_=WF-t_; WF=(l&32)?-d_:d_; }
  W[0]=q0; W[1]=Spp; W[2]=Sps; W[3]=Ss; W[4]=W8;
  W[5]=WCpp; W[6]=WCps; W[7]=WCss; W[8]=WE; W[9]=WF;
}

// ---------- main: one WAVE = one sample; 4 KB LDS/sample via phased transitions ----------
__global__ __launch_bounds__(256,6) void qm_sim(
    const float* __restrict__ x, const float* __restrict__ w_in,
    const float* __restrict__ w_fc, const float* __restrict__ wsf,
    float* __restrict__ out)
{
  __shared__ __align__(16) f2 psi[2048];               // 4 waves x 512 f2 (4 KB each)
  const int t = threadIdx.x;
  const int l = t & 63, wid = t >> 6;
  const int sample = (blockIdx.x<<2) + wid;
  char* PB = (char*)(psi + (wid<<9));
  const float* xr = x + ((size_t)sample<<10);
  const f2* G = (const f2*)wsf;                        // gates: uniform -> SGPR

  // ---- GEMV partials + norm; reduce immediately to wave-uniform (SGPR) ----
  float xq[10], n2;
  {
    float4 xv0 = *(const float4*)(xr + (l<<4));
    float4 xv1 = *(const float4*)(xr + (l<<4) + 4);
    float4 xv2 = *(const float4*)(xr + (l<<4) + 8);
    float4 xv3 = *(const float4*)(xr + (l<<4) + 12);
    f2 xc[8];
    xc[0]=mk(xv0.x,xv0.y); xc[1]=mk(xv0.z,xv0.w); xc[2]=mk(xv1.x,xv1.y); xc[3]=mk(xv1.z,xv1.w);
    xc[4]=mk(xv2.x,xv2.y); xc[5]=mk(xv2.z,xv2.w); xc[6]=mk(xv3.x,xv3.y); xc[7]=mk(xv3.z,xv3.w);
    #pragma unroll
    for (int q=0;q<10;q++){
      const float4* wr = (const float4*)(w_in + (q<<10) + (l<<4));
      float4 w0=wr[0], w1=wr[1], w2=wr[2], w3=wr[3];
      f2 a;
      a  = xc[0]*mk(w0.x,w0.y);
      a += xc[1]*mk(w0.z,w0.w);
      a += xc[2]*mk(w1.x,w1.y);
      a += xc[3]*mk(w1.z,w1.w);
      a += xc[4]*mk(w2.x,w2.y);
      a += xc[5]*mk(w2.z,w2.w);
      a += xc[6]*mk(w3.x,w3.y);
      a += xc[7]*mk(w3.z,w3.w);
      xq[q] = wave_red_bcast(a.x + a.y);               // -> uniform (SGPR)
    }
    f2 nn = xc[0]*xc[0]; nn += xc[1]*xc[1]; nn += xc[2]*xc[2]; nn += xc[3]*xc[3];
    nn += xc[4]*xc[4]; nn += xc[5]*xc[5]; nn += xc[6]*xc[6]; nn += xc[7]*xc[7];
    n2 = nn.x + nn.y;
  }
  float xs[16];
  #pragma unroll
  for (int k=0;k<16;k++) xs[k] = xr[(k<<6)|l];
  float rn = rsqrtf(wave_red_bcast(n2));

  const int Lb  = (l ^ (l>>4)) << 3;                           // no bit12
  const int L2m = (((((l>>2)<<6)) ^ (l&3) ^ (l&0xC)) << 3) & 0xFFF;
  const int L3m = ((((l<<4) ^ (l<<3)) ^ ((l ^ (l>>1)) & 15)) << 3) & 0xFFF;
  const int L3wm= (((l<<4) ^ (l&15)) << 3) & 0xFFF;
  const int L5m = (((((l>>2)<<6)) ^ ((l&3)<<2) ^ (l&0xC)) << 3) & 0xFFF;
  const bool hi = (l & 32) != 0;                               // l5

  f2 A[16], T[8];

  // ===== R1: amps from x; gates G98, G76 (regs = s9..s6) =====
  #pragma unroll
  for (int k=0;k<16;k++) A[k] = mk(xs[k]*rn, 0.f);
  gij(G+ 0, G+16, A);

  // ===== T12: write form1 (phase=k3), read form2 (phase=l5) =====
  #pragma unroll
  for (int k=0;k<8;k++) *(f2*)(PB + (Lb ^ CK1(k))) = A[k];
  WAIT_LDS;
  if (!hi){
    #pragma unroll
    for (int k=0;k<8;k++) A[k] = *(const f2*)(PB + (L2m ^ CK2(k)));
    #pragma unroll
    for (int k=0;k<8;k++) T[k] = *(const f2*)(PB + (L2m ^ CK2(k+8)));
  }
  WAIT_LDS;
  #pragma unroll
  for (int k=8;k<16;k++) *(f2*)(PB + (Lb ^ CK1(k))) = A[k];
  WAIT_LDS;
  if (hi){
    #pragma unroll
    for (int k=0;k<16;k++) A[k] = *(const f2*)(PB + (L2m ^ CK2(k)));
  } else {
    #pragma unroll
    for (int k=0;k<8;k++) A[8+k] = T[k];
  }
  WAIT_LDS;

  // ===== R2: gates G54, G32 (regs = s5..s2) =====
  gij(G+32, G+48, A);

  // ===== T23: write form2 (l5), read form3 (l5) — both lane-split =====
  if (!hi){
    #pragma unroll
    for (int k=0;k<16;k++) *(f2*)(PB + (L2m ^ CK2(k))) = A[k];
  }
  WAIT_LDS;
  if (!hi){
    #pragma unroll
    for (int k=0;k<16;k++) A[k] = *(const f2*)(PB + (L3m ^ CK3(k)));
  }
  WAIT_LDS;
  if (hi){
    #pragma unroll
    for (int k=0;k<16;k++) *(f2*)(PB + (L2m ^ CK2(k))) = A[k];
  }
  WAIT_LDS;
  if (hi){
    #pragma unroll
    for (int k=0;k<16;k++) A[k] = *(const f2*)(PB + (L3m ^ CK3(k)));
  }
  WAIT_LDS;

  // ===== R3: G10 (pre-bits 1,0, arg-swapped) + ring perm + rot32 =====
  g3(G+64, G+128, A);

  // ===== T34: write form4 (phase = l5^pj9), read form1 (phase = k3) =====
  {
    const int K03[8] = {0,3,4,7,8,11,12,15};     // pj9=0
    const int K12[8] = {1,2,5,6,9,10,13,14};     // pj9=1
    if (!hi){
      #pragma unroll
      for (int m=0;m<8;m++){ int k=K03[m]; *(f2*)(PB + (L3wm ^ CK4(k))) = A[k]; }
    } else {
      #pragma unroll
      for (int m=0;m<8;m++){ int k=K12[m]; *(f2*)(PB + (L3wm ^ CK4(k))) = A[k]; }
    }
    WAIT_LDS;
    #pragma unroll
    for (int k=0;k<8;k++) T[k] = *(const f2*)(PB + (Lb ^ CK1(k)));
    WAIT_LDS;
    if (hi){
      #pragma unroll
      for (int m=0;m<8;m++){ int k=K03[m]; *(f2*)(PB + (L3wm ^ CK4(k))) = A[k]; }
    } else {
      #pragma unroll
      for (int m=0;m<8;m++){ int k=K12[m]; *(f2*)(PB + (L3wm ^ CK4(k))) = A[k]; }
    }
    WAIT_LDS;
    #pragma unroll
    for (int k=8;k<16;k++) A[k] = *(const f2*)(PB + (Lb ^ CK1(k)));
    #pragma unroll
    for (int k=0;k<8;k++) A[k] = T[k];
    WAIT_LDS;
  }

  // ===== R4: rot98, rot76 (regs = post s9..s6) =====
  gij(G+80, G+96, A);

  // ===== T45: write form1 (k3), read form5 (l5) =====
  #pragma unroll
  for (int k=0;k<8;k++) *(f2*)(PB + (Lb ^ CK1(k))) = A[k];
  WAIT_LDS;
  if (!hi){
    #pragma unroll
    for (int k=0;k<8;k++) A[k] = *(const f2*)(PB + (L5m ^ CK5(k)));
    #pragma unroll
    for (int k=0;k<8;k++) T[k] = *(const f2*)(PB + (L5m ^ CK5(k+8)));
  }
  WAIT_LDS;
  #pragma unroll
  for (int k=8;k<16;k++) *(f2*)(PB + (Lb ^ CK1(k))) = A[k];
  WAIT_LDS;
  if (hi){
    #pragma unroll
    for (int k=0;k<16;k++) A[k] = *(const f2*)(PB + (L5m ^ CK5(k)));
  } else {
    #pragma unroll
    for (int k=0;k<8;k++) A[8+k] = T[k];
  }
  WAIT_LDS;

  // ===== R5: rot54 (i-axis), rot10 (j-axis) =====
  gij(G+112, G+144, A);

  // ===== epilogue: Walsh marginals (ring2 folded) — all in registers =====
  float W[10];
  walsh(A, l, W);

  if (l < 10){
    float o = wsf[320+l];                              // b_fc + w_fc@b_in
    const float* wf = w_fc + l*10;
    #pragma unroll
    for (int q=0;q<10;q++) o += wf[q] * (W[q] + xq[q]);
    out[(size_t)sample*10 + l] = o;
  }
}

extern "C" void kernel_launch(void* const* d_in, const int* in_sizes, int n_in,
                              void* d_out, int out_size, void* d_ws, size_t ws_size,
                              hipStream_t stream) {
  const float* x      = (const float*)d_in[0];
  const float* params = (const float*)d_in[1];
  const float* w_in   = (const float*)d_in[2];
  const float* b_in   = (const float*)d_in[3];
  const float* w_fc   = (const float*)d_in[4];
  const float* b_fc   = (const float*)d_in[5];
  float* out = (float*)d_out;

  float* wsf = (float*)d_ws;                        // 320 f gate mats + 10 f cbias

  int batch = in_sizes[0] >> 10;                    // 8192

  qm_setup<<<dim3(1), dim3(64), 0, stream>>>(params, w_fc, b_in, b_fc, wsf);
  qm_sim<<<dim3(batch>>2), dim3(256), 0, stream>>>(x, w_in, w_fc, wsf, out);
}